// Round 1
// baseline (12529.131 us; speedup 1.0000x reference)
//
#include <hip/hip_runtime.h>
#include <hip/hip_bf16.h>
#include <hip/hip_cooperative_groups.h>

namespace cg = cooperative_groups;

// HeteroGNN R4:
// - agg: persistent cooperative kernel; bucket-phase lockstep enforced with
//   grid.sync() per src bucket so every XCD gathers from the same 4MB slice
//   of H (per-XCD-L2-resident). 10 dsts/wave in register accumulators,
//   2 chunks x 13 buckets = 26 grid syncs per agg. Non-temporal epack loads
//   and output stores keep the streaming traffic from evicting the bucket.
// - GEMM unchanged (8x8 register blocking, transposed padded A-tile).

#define RELS 4
#define HDIM 256
#define NB 16          // src buckets per dst (src>>13, src<100000 -> 0..12)
#define BSH 13
#define DPW 10         // dst nodes per wave in cooperative agg

typedef float f32x4_t __attribute__((ext_vector_type(4)));

struct EdgePtrs {
    const int*   ei[RELS];
    const float* ew[RELS];
};

__device__ inline unsigned short f32_to_bf16_rne(float f) {
    unsigned int u = __float_as_uint(f);
    unsigned int r = 0x7FFFu + ((u >> 16) & 1u);
    return (unsigned short)((u + r) >> 16);
}

// ---------------- CSR build (keys = dst*NB + src_bucket) ----------------

__global__ __launch_bounds__(256) void count_kernel(EdgePtrs ep, int* __restrict__ cnts, int E) {
    int bpr = gridDim.x >> 2;
    int rel = blockIdx.x / bpr;
    int e = (blockIdx.x - rel * bpr) * 256 + threadIdx.x;
    if (e < E) {
        int src = ep.ei[rel][e];
        int dst = ep.ei[rel][E + e];
        atomicAdd(&cnts[(dst << 4) | (src >> BSH)], 1);
    }
}

template <int ITEMS>
__global__ __launch_bounds__(256) void scan_kernel(const int* __restrict__ in, int* __restrict__ out,
                                                   int* __restrict__ blockSums, int n) {
    __shared__ int wsum[4];
    int t = threadIdx.x;
    int base = blockIdx.x * 256 * ITEMS;
    int idx0 = base + t * ITEMS;
    int v[ITEMS];
    int local = 0;
#pragma unroll
    for (int j = 0; j < ITEMS; ++j) {
        v[j] = (idx0 + j < n) ? in[idx0 + j] : 0;
        local += v[j];
    }
    int lane = t & 63;
    int incl = local;
#pragma unroll
    for (int off = 1; off < 64; off <<= 1) {
        int y = __shfl_up(incl, off, 64);
        if (lane >= off) incl += y;
    }
    int waveId = t >> 6;
    if (lane == 63) wsum[waveId] = incl;
    __syncthreads();
    int waveOff = 0;
    for (int wi = 0; wi < waveId; ++wi) waveOff += wsum[wi];
    int run = waveOff + incl - local;
#pragma unroll
    for (int j = 0; j < ITEMS; ++j) {
        if (idx0 + j < n) out[idx0 + j] = run;
        run += v[j];
    }
    if (t == 255 && blockSums) blockSums[blockIdx.x] = waveOff + incl;
}

__global__ __launch_bounds__(256) void add_off_kernel(int* __restrict__ offs, const int* __restrict__ bsums,
                                                      int* __restrict__ cursor, int n) {
    int i = blockIdx.x * 256 + threadIdx.x;
    if (i < n) {
        int o = offs[i] + bsums[i >> 11];   // 2048 elems per L0 scan block
        offs[i] = o;
        cursor[i] = o;
    }
}

__global__ __launch_bounds__(256) void fill_kernel(EdgePtrs ep, int* __restrict__ cursor,
                                                   int2* __restrict__ epack, int E) {
    int bpr = gridDim.x >> 2;
    int rel = blockIdx.x / bpr;
    int e = (blockIdx.x - rel * bpr) * 256 + threadIdx.x;
    if (e < E) {
        int src = ep.ei[rel][e];
        int dst = ep.ei[rel][E + e];
        float w = ep.ew[rel][e];
        int pos = atomicAdd(&cursor[(dst << 4) | (src >> BSH)], 1);
        epack[pos] = make_int2(src, __float_as_int(w));
    }
}

// ---------------- GEMM: [M,K] x [K,256] -> bf16 [M,256] ----------------

template <int K, bool FUSE>
__global__ __launch_bounds__(256) void gemm_kernel(const float* __restrict__ A, const float* __restrict__ W,
                                                   unsigned short* __restrict__ out, int M,
                                                   const float* __restrict__ stats,
                                                   const float* __restrict__ lnw, const float* __restrict__ lnb,
                                                   float invM) {
    __shared__ float At[K * 68];
    int t = threadIdx.x;
    int rowBase = blockIdx.x * 64;
    float m = 0.f, inv = 1.f;
    if (FUSE) {
        float s = stats[0], ss = stats[1];
        m = s * invM;
        float var = ss * invM - m * m;
        inv = 1.f / (sqrtf(fmaxf(var, 0.f)) + 1e-5f);
    }
    constexpr int KQ = K / 4;
    for (int idx = t; idx < 64 * KQ; idx += 256) {
        int row = idx / KQ;
        int kq = idx - row * KQ;
        int grow = rowBase + row;
        float4 a = make_float4(0.f, 0.f, 0.f, 0.f);
        if (grow < M) a = *(const float4*)&A[(size_t)grow * K + kq * 4];
        if (FUSE) {
            float4 w4 = *(const float4*)&lnw[kq * 4];
            float4 b4 = *(const float4*)&lnb[kq * 4];
            a.x = (a.x - m) * inv * w4.x + b4.x;
            a.y = (a.y - m) * inv * w4.y + b4.y;
            a.z = (a.z - m) * inv * w4.z + b4.z;
            a.w = (a.w - m) * inv * w4.w + b4.w;
        }
        At[(kq * 4 + 0) * 68 + row] = a.x;
        At[(kq * 4 + 1) * 68 + row] = a.y;
        At[(kq * 4 + 2) * 68 + row] = a.z;
        At[(kq * 4 + 3) * 68 + row] = a.w;
    }
    __syncthreads();

    int tx = t & 31;        // col base
    int ty = t >> 5;        // row group (8 rows)
    float acc[8][8];
#pragma unroll
    for (int i = 0; i < 8; ++i)
#pragma unroll
        for (int j = 0; j < 8; ++j) acc[i][j] = 0.f;

#pragma unroll 4
    for (int k = 0; k < K; ++k) {
        float4 a0 = *(const float4*)&At[k * 68 + (ty << 3)];
        float4 a1 = *(const float4*)&At[k * 68 + (ty << 3) + 4];
        float wv[8];
#pragma unroll
        for (int j = 0; j < 8; ++j) wv[j] = W[k * HDIM + tx + (j << 5)];
#pragma unroll
        for (int j = 0; j < 8; ++j) {
            acc[0][j] += a0.x * wv[j];
            acc[1][j] += a0.y * wv[j];
            acc[2][j] += a0.z * wv[j];
            acc[3][j] += a0.w * wv[j];
            acc[4][j] += a1.x * wv[j];
            acc[5][j] += a1.y * wv[j];
            acc[6][j] += a1.z * wv[j];
            acc[7][j] += a1.w * wv[j];
        }
    }
#pragma unroll
    for (int i = 0; i < 8; ++i) {
        int row = rowBase + (ty << 3) + i;
        if (row < M) {
#pragma unroll
            for (int j = 0; j < 8; ++j)
                out[((size_t)row << 8) + tx + (j << 5)] = f32_to_bf16_rne(acc[i][j]);
        }
    }
}

// ---------------- Aggregation ----------------

__device__ inline void acc_edge(float4& acc, float w, ushort4 u) {
    acc.x += w * __uint_as_float((unsigned)u.x << 16);
    acc.y += w * __uint_as_float((unsigned)u.y << 16);
    acc.z += w * __uint_as_float((unsigned)u.z << 16);
    acc.w += w * __uint_as_float((unsigned)u.w << 16);
}

// Cooperative bucket-phased aggregation: all waves process src-bucket b
// between grid syncs -> gathers are per-XCD-L2-resident (4MB bucket).
__global__ __launch_bounds__(256, 6) void agg_coop(const unsigned short* __restrict__ Hf,
                                                   const int* __restrict__ offs,
                                                   const int2* __restrict__ epack,
                                                   const float* __restrict__ bias,
                                                   float* __restrict__ outp,
                                                   float* __restrict__ stats,
                                                   int nNodes) {
    cg::grid_group grid = cg::this_grid();
    const int nwaves = (int)((gridDim.x * blockDim.x) >> 6);
    const int gwave = (int)((blockIdx.x * blockDim.x + threadIdx.x) >> 6);
    const int lane = threadIdx.x & 63;
    const int c = lane << 2;
    const int nbuck = (nNodes + ((1 << BSH) - 1)) >> BSH;   // 13
    float sum = 0.f, ssq = 0.f;
    int chunkBase = 0, cidx = 0;
    while (chunkBase < nNodes) {
        int rem = nNodes - chunkBase;
        int dpw = (rem + nwaves - 1) / nwaves;
        if (dpw > DPW) dpw = DPW;
        int d0 = chunkBase + gwave * dpw;
        float4 b4 = *(const float4*)&bias[c];
        float4 acc[DPW];
#pragma unroll
        for (int j = 0; j < DPW; ++j) acc[j] = b4;
        for (int b = 0; b < nbuck; ++b) {
            // alternate sweep direction per chunk: reuse last bucket in L2
            int bb = (cidx & 1) ? (nbuck - 1 - b) : b;
#pragma unroll
            for (int j = 0; j < DPW; ++j) {
                int d = d0 + j;
                if (j < dpw && d < nNodes) {
                    int key = (d << 4) | bb;
                    int start = __builtin_amdgcn_readfirstlane(offs[key]);
                    int cnt = __builtin_amdgcn_readfirstlane(offs[key + 1]) - start;
                    const long long* ep = (const long long*)(epack + start);
                    int i = 0;
                    for (; i + 2 <= cnt; i += 2) {
                        long long q0 = __builtin_nontemporal_load(ep + i);
                        long long q1 = __builtin_nontemporal_load(ep + i + 1);
                        ushort4 u0 = *(const ushort4*)&Hf[((size_t)(unsigned)(int)q0 << 8) + c];
                        ushort4 u1 = *(const ushort4*)&Hf[((size_t)(unsigned)(int)q1 << 8) + c];
                        acc_edge(acc[j], __int_as_float((int)(q0 >> 32)), u0);
                        acc_edge(acc[j], __int_as_float((int)(q1 >> 32)), u1);
                    }
                    if (i < cnt) {
                        long long q0 = __builtin_nontemporal_load(ep + i);
                        ushort4 u0 = *(const ushort4*)&Hf[((size_t)(unsigned)(int)q0 << 8) + c];
                        acc_edge(acc[j], __int_as_float((int)(q0 >> 32)), u0);
                    }
                }
            }
            grid.sync();
        }
#pragma unroll
        for (int j = 0; j < DPW; ++j) {
            int d = d0 + j;
            if (j < dpw && d < nNodes) {
                sum += acc[j].x + acc[j].y + acc[j].z + acc[j].w;
                ssq += acc[j].x * acc[j].x + acc[j].y * acc[j].y +
                       acc[j].z * acc[j].z + acc[j].w * acc[j].w;
                f32x4_t v = {acc[j].x, acc[j].y, acc[j].z, acc[j].w};
                __builtin_nontemporal_store(v, (f32x4_t*)(outp + (((size_t)d) << 8) + c));
            }
        }
        chunkBase += nwaves * dpw;
        ++cidx;
    }
#pragma unroll
    for (int off = 32; off > 0; off >>= 1) {
        sum += __shfl_down(sum, off, 64);
        ssq += __shfl_down(ssq, off, 64);
    }
    __shared__ float ls[8];
    int wid = threadIdx.x >> 6;
    if (lane == 0) { ls[wid] = sum; ls[4 + wid] = ssq; }
    __syncthreads();
    if (threadIdx.x == 0) {
        atomicAdd(&stats[0], ls[0] + ls[1] + ls[2] + ls[3]);
        atomicAdd(&stats[1], ls[4] + ls[5] + ls[6] + ls[7]);
    }
}

// Fallback (non-cooperative) aggregation: one wave per dst node.
__global__ __launch_bounds__(256) void agg_kernel(const unsigned short* __restrict__ Hf,
                                                  const int* __restrict__ offs,
                                                  const int2* __restrict__ epack,
                                                  const float* __restrict__ bias,
                                                  float* __restrict__ outp, float* __restrict__ stats,
                                                  int nNodes, int totE) {
    int gwave = (blockIdx.x << 2) | (threadIdx.x >> 6);
    int lane = threadIdx.x & 63;
    int c = lane << 2;
    float4 acc = make_float4(0.f, 0.f, 0.f, 0.f);
    if (gwave < nNodes) {
        acc = *(const float4*)&bias[c];
        int start = __builtin_amdgcn_readfirstlane(offs[gwave << 4]);
        int endv = (gwave + 1 < nNodes) ? offs[(gwave + 1) << 4] : totE;
        int cnt = __builtin_amdgcn_readfirstlane(endv) - start;
        const int2* ep = epack + start;
        int i = 0;
        for (; i + 8 <= cnt; i += 8) {
            int2 p0 = ep[i], p1 = ep[i + 1], p2 = ep[i + 2], p3 = ep[i + 3];
            int2 p4 = ep[i + 4], p5 = ep[i + 5], p6 = ep[i + 6], p7 = ep[i + 7];
            ushort4 u0 = *(const ushort4*)&Hf[((size_t)p0.x << 8) + c];
            ushort4 u1 = *(const ushort4*)&Hf[((size_t)p1.x << 8) + c];
            ushort4 u2 = *(const ushort4*)&Hf[((size_t)p2.x << 8) + c];
            ushort4 u3 = *(const ushort4*)&Hf[((size_t)p3.x << 8) + c];
            ushort4 u4 = *(const ushort4*)&Hf[((size_t)p4.x << 8) + c];
            ushort4 u5 = *(const ushort4*)&Hf[((size_t)p5.x << 8) + c];
            ushort4 u6 = *(const ushort4*)&Hf[((size_t)p6.x << 8) + c];
            ushort4 u7 = *(const ushort4*)&Hf[((size_t)p7.x << 8) + c];
            acc_edge(acc, __int_as_float(p0.y), u0);
            acc_edge(acc, __int_as_float(p1.y), u1);
            acc_edge(acc, __int_as_float(p2.y), u2);
            acc_edge(acc, __int_as_float(p3.y), u3);
            acc_edge(acc, __int_as_float(p4.y), u4);
            acc_edge(acc, __int_as_float(p5.y), u5);
            acc_edge(acc, __int_as_float(p6.y), u6);
            acc_edge(acc, __int_as_float(p7.y), u7);
        }
        for (; i < cnt; ++i) {
            int2 p = ep[i];
            ushort4 u = *(const ushort4*)&Hf[((size_t)p.x << 8) + c];
            acc_edge(acc, __int_as_float(p.y), u);
        }
        *(float4*)&outp[((size_t)gwave << 8) + c] = acc;
    }
    float s = acc.x + acc.y + acc.z + acc.w;
    float ss = acc.x * acc.x + acc.y * acc.y + acc.z * acc.z + acc.w * acc.w;
#pragma unroll
    for (int off = 32; off > 0; off >>= 1) {
        s += __shfl_down(s, off, 64);
        ss += __shfl_down(ss, off, 64);
    }
    __shared__ float ls[8];
    int wid = threadIdx.x >> 6;
    if (lane == 0) { ls[wid] = s; ls[4 + wid] = ss; }
    __syncthreads();
    if (threadIdx.x == 0) {
        atomicAdd(&stats[0], ls[0] + ls[1] + ls[2] + ls[3]);
        atomicAdd(&stats[1], ls[4] + ls[5] + ls[6] + ls[7]);
    }
}

// ---------------- Graph LayerNorm (elementwise, in-place, final) ----------------

__global__ __launch_bounds__(256) void ln_kernel(float* __restrict__ data, const float* __restrict__ stats,
                                                 const float* __restrict__ lw, const float* __restrict__ lb,
                                                 long long total, float invM) {
    long long i4 = (long long)blockIdx.x * 256 + threadIdx.x;
    long long idx = i4 * 4;
    if (idx >= total) return;
    float m = stats[0] * invM;
    float var = stats[1] * invM - m * m;
    float inv = 1.f / (sqrtf(fmaxf(var, 0.f)) + 1e-5f);
    float4 v = *(float4*)&data[idx];
    int c = (int)(idx & (HDIM - 1));
    float4 w = *(const float4*)&lw[c];
    float4 b = *(const float4*)&lb[c];
    v.x = (v.x - m) * inv * w.x + b.x;
    v.y = (v.y - m) * inv * w.y + b.y;
    v.z = (v.z - m) * inv * w.z + b.z;
    v.w = (v.w - m) * inv * w.w + b.w;
    *(float4*)&data[idx] = v;
}

// ---------------- launch ----------------

extern "C" void kernel_launch(void* const* d_in, const int* in_sizes, int n_in,
                              void* d_out, int out_size, void* d_ws, size_t ws_size,
                              hipStream_t stream) {
    const float* x = (const float*)d_in[0];
    EdgePtrs ep;
    ep.ei[0] = (const int*)d_in[1]; ep.ew[0] = (const float*)d_in[2];
    ep.ei[1] = (const int*)d_in[3]; ep.ew[1] = (const float*)d_in[4];
    ep.ei[2] = (const int*)d_in[5]; ep.ew[2] = (const float*)d_in[6];
    ep.ei[3] = (const int*)d_in[7]; ep.ew[3] = (const float*)d_in[8];
    const float* W1 = (const float*)d_in[9];
    const float* b1 = (const float*)d_in[10];
    const float* W2 = (const float*)d_in[11];
    const float* b2 = (const float*)d_in[12];
    const float* ln1w = (const float*)d_in[13];
    const float* ln1b = (const float*)d_in[14];
    const float* ln2w = (const float*)d_in[15];
    const float* ln2b = (const float*)d_in[16];

    const int N = in_sizes[0] / 128;  // 100000
    const int E = in_sizes[2];        // 1600000
    const int totE = RELS * E;
    const int nKeys = N * NB;         // 1.6M
    float* out = (float*)d_out;

    // workspace layout
    char* ws = (char*)d_ws;
    unsigned short* Hbuf = (unsigned short*)ws;        // N*256 bf16 (51.2 MB)
    int2* epack = (int2*)(Hbuf + (size_t)N * HDIM);    // totE int2 (51.2 MB)
    int* cnts = (int*)(epack + totE);                  // nKeys (6.4 MB)
    int* offs = cnts + nKeys;                          // nKeys
    int* cursor = offs + nKeys;                        // nKeys
    int* bsums = cursor + nKeys;                       // 1024
    float* stats = (float*)(bsums + 1024);             // 4 floats

    // cooperative grid size: resident blocks for agg_coop (cached)
    static int coopBlocks = 0;
    if (coopBlocks == 0) {
        int perCU = 0;
        if (hipOccupancyMaxActiveBlocksPerMultiprocessor(
                &perCU, reinterpret_cast<const void*>(&agg_coop), 256, 0) != hipSuccess ||
            perCU <= 0)
            perCU = 4;
        if (perCU > 8) perCU = 8;
        int cus = 256;
        hipDeviceProp_t prop;
        if (hipGetDeviceProperties(&prop, 0) == hipSuccess && prop.multiProcessorCount > 0)
            cus = prop.multiProcessorCount;
        coopBlocks = perCU * cus;
    }

    hipMemsetAsync(cnts, 0, (size_t)nKeys * sizeof(int), stream);
    hipMemsetAsync(stats, 0, 4 * sizeof(float), stream);

    int bpr = (E + 255) / 256;
    count_kernel<<<RELS * bpr, 256, 0, stream>>>(ep, cnts, E);
    int nb1 = (nKeys + 2047) / 2048;   // 782 L0 blocks (ITEMS=8)
    scan_kernel<8><<<nb1, 256, 0, stream>>>(cnts, offs, bsums, nKeys);
    scan_kernel<4><<<1, 256, 0, stream>>>(bsums, bsums, nullptr, nb1);
    add_off_kernel<<<(nKeys + 255) / 256, 256, 0, stream>>>(offs, bsums, cursor, nKeys);
    fill_kernel<<<RELS * bpr, 256, 0, stream>>>(ep, cursor, epack, E);

    long long total = (long long)N * HDIM;
    float invM = 1.f / (float)total;
    int gemmGrid = (N + 63) / 64;
    int aggGrid = (N + 3) / 4;
    int lnGrid = (int)((total / 4 + 255) / 256);

    // Layer 1: x@W1 -> Hbuf(bf16) ; agg -> d_out (+stats0)
    gemm_kernel<128, false><<<gemmGrid, 256, 0, stream>>>(x, W1, Hbuf, N, nullptr, nullptr, nullptr, invM);
    {
        const unsigned short* a0 = Hbuf; const int* a1 = offs; const int2* a2 = epack;
        const float* a3 = b1; float* a4 = out; float* a5 = stats; int a6 = N;
        void* cargs[] = {&a0, &a1, &a2, &a3, &a4, &a5, &a6};
        if (hipLaunchCooperativeKernel(reinterpret_cast<const void*>(&agg_coop),
                                       dim3(coopBlocks), dim3(256), cargs, 0, stream) != hipSuccess)
            agg_kernel<<<aggGrid, 256, 0, stream>>>(Hbuf, offs, epack, b1, out, stats, N, totE);
    }

    // Layer 2: LN1 fused into GEMM2 staging ; agg -> d_out (+stats1) ; LN2
    gemm_kernel<256, true><<<gemmGrid, 256, 0, stream>>>(out, W2, Hbuf, N, stats, ln1w, ln1b, invM);
    {
        const unsigned short* a0 = Hbuf; const int* a1 = offs; const int2* a2 = epack;
        const float* a3 = b2; float* a4 = out; float* a5 = stats + 2; int a6 = N;
        void* cargs[] = {&a0, &a1, &a2, &a3, &a4, &a5, &a6};
        if (hipLaunchCooperativeKernel(reinterpret_cast<const void*>(&agg_coop),
                                       dim3(coopBlocks), dim3(256), cargs, 0, stream) != hipSuccess)
            agg_kernel<<<aggGrid, 256, 0, stream>>>(Hbuf, offs, epack, b2, out, stats + 2, N, totE);
    }
    ln_kernel<<<lnGrid, 256, 0, stream>>>(out, stats + 2, ln2w, ln2b, total, invM);
}

// Round 2
// 2667.977 us; speedup vs baseline: 4.6961x; 4.6961x over previous
//
#include <hip/hip_runtime.h>
#include <hip/hip_bf16.h>

// HeteroGNN R5:
// - agg (R4 coop reverted): dst-per-wave gather, but 2 edges per gather
//   instruction (dwordx4, 32 lanes/row) and 12 edges in flight per wave ->
//   ~2x rows-in-flight per CU vs R3. R4 showed bytes aren't the limit
//   (FETCH 1.5GB->0.6GB made it 7x SLOWER via grid.sync starvation);
//   the limit is MLP/request throughput.
// - GEMM unchanged (8x8 register blocking, transposed padded A-tile).

#define RELS 4
#define HDIM 256
#define NB 16          // src buckets per dst (src>>13, src<100000 -> 0..12)
#define BSH 13

typedef float f32x4_t __attribute__((ext_vector_type(4)));
typedef unsigned short u16x8_t __attribute__((ext_vector_type(8)));

struct EdgePtrs {
    const int*   ei[RELS];
    const float* ew[RELS];
};

__device__ inline unsigned short f32_to_bf16_rne(float f) {
    unsigned int u = __float_as_uint(f);
    unsigned int r = 0x7FFFu + ((u >> 16) & 1u);
    return (unsigned short)((u + r) >> 16);
}

// ---------------- CSR build (keys = dst*NB + src_bucket) ----------------

__global__ __launch_bounds__(256) void count_kernel(EdgePtrs ep, int* __restrict__ cnts, int E) {
    int bpr = gridDim.x >> 2;
    int rel = blockIdx.x / bpr;
    int e = (blockIdx.x - rel * bpr) * 256 + threadIdx.x;
    if (e < E) {
        int src = ep.ei[rel][e];
        int dst = ep.ei[rel][E + e];
        atomicAdd(&cnts[(dst << 4) | (src >> BSH)], 1);
    }
}

template <int ITEMS>
__global__ __launch_bounds__(256) void scan_kernel(const int* __restrict__ in, int* __restrict__ out,
                                                   int* __restrict__ blockSums, int n) {
    __shared__ int wsum[4];
    int t = threadIdx.x;
    int base = blockIdx.x * 256 * ITEMS;
    int idx0 = base + t * ITEMS;
    int v[ITEMS];
    int local = 0;
#pragma unroll
    for (int j = 0; j < ITEMS; ++j) {
        v[j] = (idx0 + j < n) ? in[idx0 + j] : 0;
        local += v[j];
    }
    int lane = t & 63;
    int incl = local;
#pragma unroll
    for (int off = 1; off < 64; off <<= 1) {
        int y = __shfl_up(incl, off, 64);
        if (lane >= off) incl += y;
    }
    int waveId = t >> 6;
    if (lane == 63) wsum[waveId] = incl;
    __syncthreads();
    int waveOff = 0;
    for (int wi = 0; wi < waveId; ++wi) waveOff += wsum[wi];
    int run = waveOff + incl - local;
#pragma unroll
    for (int j = 0; j < ITEMS; ++j) {
        if (idx0 + j < n) out[idx0 + j] = run;
        run += v[j];
    }
    if (t == 255 && blockSums) blockSums[blockIdx.x] = waveOff + incl;
}

__global__ __launch_bounds__(256) void add_off_kernel(int* __restrict__ offs, const int* __restrict__ bsums,
                                                      int* __restrict__ cursor, int n) {
    int i = blockIdx.x * 256 + threadIdx.x;
    if (i < n) {
        int o = offs[i] + bsums[i >> 11];   // 2048 elems per L0 scan block
        offs[i] = o;
        cursor[i] = o;
    }
}

__global__ __launch_bounds__(256) void fill_kernel(EdgePtrs ep, int* __restrict__ cursor,
                                                   int2* __restrict__ epack, int E) {
    int bpr = gridDim.x >> 2;
    int rel = blockIdx.x / bpr;
    int e = (blockIdx.x - rel * bpr) * 256 + threadIdx.x;
    if (e < E) {
        int src = ep.ei[rel][e];
        int dst = ep.ei[rel][E + e];
        float w = ep.ew[rel][e];
        int pos = atomicAdd(&cursor[(dst << 4) | (src >> BSH)], 1);
        epack[pos] = make_int2(src, __float_as_int(w));
    }
}

// ---------------- GEMM: [M,K] x [K,256] -> bf16 [M,256] ----------------

template <int K, bool FUSE>
__global__ __launch_bounds__(256) void gemm_kernel(const float* __restrict__ A, const float* __restrict__ W,
                                                   unsigned short* __restrict__ out, int M,
                                                   const float* __restrict__ stats,
                                                   const float* __restrict__ lnw, const float* __restrict__ lnb,
                                                   float invM) {
    __shared__ float At[K * 68];
    int t = threadIdx.x;
    int rowBase = blockIdx.x * 64;
    float m = 0.f, inv = 1.f;
    if (FUSE) {
        float s = stats[0], ss = stats[1];
        m = s * invM;
        float var = ss * invM - m * m;
        inv = 1.f / (sqrtf(fmaxf(var, 0.f)) + 1e-5f);
    }
    constexpr int KQ = K / 4;
    for (int idx = t; idx < 64 * KQ; idx += 256) {
        int row = idx / KQ;
        int kq = idx - row * KQ;
        int grow = rowBase + row;
        float4 a = make_float4(0.f, 0.f, 0.f, 0.f);
        if (grow < M) a = *(const float4*)&A[(size_t)grow * K + kq * 4];
        if (FUSE) {
            float4 w4 = *(const float4*)&lnw[kq * 4];
            float4 b4 = *(const float4*)&lnb[kq * 4];
            a.x = (a.x - m) * inv * w4.x + b4.x;
            a.y = (a.y - m) * inv * w4.y + b4.y;
            a.z = (a.z - m) * inv * w4.z + b4.z;
            a.w = (a.w - m) * inv * w4.w + b4.w;
        }
        At[(kq * 4 + 0) * 68 + row] = a.x;
        At[(kq * 4 + 1) * 68 + row] = a.y;
        At[(kq * 4 + 2) * 68 + row] = a.z;
        At[(kq * 4 + 3) * 68 + row] = a.w;
    }
    __syncthreads();

    int tx = t & 31;        // col base
    int ty = t >> 5;        // row group (8 rows)
    float acc[8][8];
#pragma unroll
    for (int i = 0; i < 8; ++i)
#pragma unroll
        for (int j = 0; j < 8; ++j) acc[i][j] = 0.f;

#pragma unroll 4
    for (int k = 0; k < K; ++k) {
        float4 a0 = *(const float4*)&At[k * 68 + (ty << 3)];
        float4 a1 = *(const float4*)&At[k * 68 + (ty << 3) + 4];
        float wv[8];
#pragma unroll
        for (int j = 0; j < 8; ++j) wv[j] = W[k * HDIM + tx + (j << 5)];
#pragma unroll
        for (int j = 0; j < 8; ++j) {
            acc[0][j] += a0.x * wv[j];
            acc[1][j] += a0.y * wv[j];
            acc[2][j] += a0.z * wv[j];
            acc[3][j] += a0.w * wv[j];
            acc[4][j] += a1.x * wv[j];
            acc[5][j] += a1.y * wv[j];
            acc[6][j] += a1.z * wv[j];
            acc[7][j] += a1.w * wv[j];
        }
    }
#pragma unroll
    for (int i = 0; i < 8; ++i) {
        int row = rowBase + (ty << 3) + i;
        if (row < M) {
#pragma unroll
            for (int j = 0; j < 8; ++j)
                out[((size_t)row << 8) + tx + (j << 5)] = f32_to_bf16_rne(acc[i][j]);
        }
    }
}

// ---------------- Aggregation: one wave per dst, 2 edges per gather ----------------
// Lane L: half = L>>5 selects edge parity within a pair; cl = L&31 selects the
// 16B slice (8 bf16 channels) of the 512B row. Per-lane acc covers channels
// cl*8..cl*8+7; halves combined with shfl_xor(32) at the end.

__device__ inline void acc_fma8(float* a, float w, u16x8_t u) {
#pragma unroll
    for (int k = 0; k < 8; ++k)
        a[k] += w * __uint_as_float((unsigned)u[k] << 16);
}

__global__ __launch_bounds__(256) void agg_kernel(const unsigned short* __restrict__ Hf,
                                                  const int* __restrict__ offs,
                                                  const int2* __restrict__ epack,
                                                  const float* __restrict__ bias,
                                                  float* __restrict__ outp, float* __restrict__ stats,
                                                  int nNodes, int totE) {
    int gwave = (blockIdx.x << 2) | (threadIdx.x >> 6);
    int lane = threadIdx.x & 63;
    int half = lane >> 5;
    int cl = lane & 31;
    const unsigned short* __restrict__ hbase = Hf + cl * 8;

    float a[8];
#pragma unroll
    for (int k = 0; k < 8; ++k) a[k] = 0.f;

    if (gwave < nNodes) {
        int start = __builtin_amdgcn_readfirstlane(offs[gwave << 4]);
        int endv = (gwave + 1 < nNodes) ? offs[(gwave + 1) << 4] : totE;
        int cnt = __builtin_amdgcn_readfirstlane(endv) - start;
        const long long* ep = (const long long*)epack + start;
        int i = 0;
        // 12 edges in flight: 6 per-lane edge loads + 6 paired row gathers
        for (; i + 12 <= cnt; i += 12) {
            long long q[6];
#pragma unroll
            for (int t = 0; t < 6; ++t) q[t] = ep[i + 2 * t + half];
            u16x8_t u[6];
#pragma unroll
            for (int t = 0; t < 6; ++t)
                u[t] = *(const u16x8_t*)&hbase[((size_t)(int)q[t]) << 8];
#pragma unroll
            for (int t = 0; t < 6; ++t)
                acc_fma8(a, __int_as_float((int)(q[t] >> 32)), u[t]);
        }
        for (; i + 2 <= cnt; i += 2) {
            long long q = ep[i + half];
            u16x8_t u = *(const u16x8_t*)&hbase[((size_t)(int)q) << 8];
            acc_fma8(a, __int_as_float((int)(q >> 32)), u);
        }
        if (i < cnt) {  // odd tail: both halves load same row, upper half w=0
            long long q = ep[i];
            u16x8_t u = *(const u16x8_t*)&hbase[((size_t)(int)q) << 8];
            float w = half ? 0.f : __int_as_float((int)(q >> 32));
            acc_fma8(a, w, u);
        }
    }
    // combine even/odd halves: lane L += lane L^32
#pragma unroll
    for (int k = 0; k < 8; ++k) a[k] += __shfl_xor(a[k], 32, 64);

    float sum = 0.f, ssq = 0.f;
    if (gwave < nNodes) {
        float4 b0 = *(const float4*)&bias[cl * 8];
        float4 b1 = *(const float4*)&bias[cl * 8 + 4];
        a[0] += b0.x; a[1] += b0.y; a[2] += b0.z; a[3] += b0.w;
        a[4] += b1.x; a[5] += b1.y; a[6] += b1.z; a[7] += b1.w;
        if (half == 0) {
            f32x4_t v0 = {a[0], a[1], a[2], a[3]};
            f32x4_t v1 = {a[4], a[5], a[6], a[7]};
            *(f32x4_t*)&outp[((size_t)gwave << 8) + cl * 8] = v0;
            *(f32x4_t*)&outp[((size_t)gwave << 8) + cl * 8 + 4] = v1;
#pragma unroll
            for (int k = 0; k < 8; ++k) { sum += a[k]; ssq += a[k] * a[k]; }
        }
    }
#pragma unroll
    for (int off = 32; off > 0; off >>= 1) {
        sum += __shfl_down(sum, off, 64);
        ssq += __shfl_down(ssq, off, 64);
    }
    __shared__ float ls[8];
    int wid = threadIdx.x >> 6;
    if ((threadIdx.x & 63) == 0) { ls[wid] = sum; ls[4 + wid] = ssq; }
    __syncthreads();
    if (threadIdx.x == 0) {
        atomicAdd(&stats[0], ls[0] + ls[1] + ls[2] + ls[3]);
        atomicAdd(&stats[1], ls[4] + ls[5] + ls[6] + ls[7]);
    }
}

// ---------------- Graph LayerNorm (elementwise, in-place, final) ----------------

__global__ __launch_bounds__(256) void ln_kernel(float* __restrict__ data, const float* __restrict__ stats,
                                                 const float* __restrict__ lw, const float* __restrict__ lb,
                                                 long long total, float invM) {
    long long i4 = (long long)blockIdx.x * 256 + threadIdx.x;
    long long idx = i4 * 4;
    if (idx >= total) return;
    float m = stats[0] * invM;
    float var = stats[1] * invM - m * m;
    float inv = 1.f / (sqrtf(fmaxf(var, 0.f)) + 1e-5f);
    float4 v = *(float4*)&data[idx];
    int c = (int)(idx & (HDIM - 1));
    float4 w = *(const float4*)&lw[c];
    float4 b = *(const float4*)&lb[c];
    v.x = (v.x - m) * inv * w.x + b.x;
    v.y = (v.y - m) * inv * w.y + b.y;
    v.z = (v.z - m) * inv * w.z + b.z;
    v.w = (v.w - m) * inv * w.w + b.w;
    *(float4*)&data[idx] = v;
}

// ---------------- launch ----------------

extern "C" void kernel_launch(void* const* d_in, const int* in_sizes, int n_in,
                              void* d_out, int out_size, void* d_ws, size_t ws_size,
                              hipStream_t stream) {
    const float* x = (const float*)d_in[0];
    EdgePtrs ep;
    ep.ei[0] = (const int*)d_in[1]; ep.ew[0] = (const float*)d_in[2];
    ep.ei[1] = (const int*)d_in[3]; ep.ew[1] = (const float*)d_in[4];
    ep.ei[2] = (const int*)d_in[5]; ep.ew[2] = (const float*)d_in[6];
    ep.ei[3] = (const int*)d_in[7]; ep.ew[3] = (const float*)d_in[8];
    const float* W1 = (const float*)d_in[9];
    const float* b1 = (const float*)d_in[10];
    const float* W2 = (const float*)d_in[11];
    const float* b2 = (const float*)d_in[12];
    const float* ln1w = (const float*)d_in[13];
    const float* ln1b = (const float*)d_in[14];
    const float* ln2w = (const float*)d_in[15];
    const float* ln2b = (const float*)d_in[16];

    const int N = in_sizes[0] / 128;  // 100000
    const int E = in_sizes[2];        // 1600000
    const int totE = RELS * E;
    const int nKeys = N * NB;         // 1.6M
    float* out = (float*)d_out;

    // workspace layout
    char* ws = (char*)d_ws;
    unsigned short* Hbuf = (unsigned short*)ws;        // N*256 bf16 (51.2 MB)
    int2* epack = (int2*)(Hbuf + (size_t)N * HDIM);    // totE int2 (51.2 MB)
    int* cnts = (int*)(epack + totE);                  // nKeys (6.4 MB)
    int* offs = cnts + nKeys;                          // nKeys
    int* cursor = offs + nKeys;                        // nKeys
    int* bsums = cursor + nKeys;                       // 1024
    float* stats = (float*)(bsums + 1024);             // 4 floats

    hipMemsetAsync(cnts, 0, (size_t)nKeys * sizeof(int), stream);
    hipMemsetAsync(stats, 0, 4 * sizeof(float), stream);

    int bpr = (E + 255) / 256;
    count_kernel<<<RELS * bpr, 256, 0, stream>>>(ep, cnts, E);
    int nb1 = (nKeys + 2047) / 2048;   // 782 L0 blocks (ITEMS=8)
    scan_kernel<8><<<nb1, 256, 0, stream>>>(cnts, offs, bsums, nKeys);
    scan_kernel<4><<<1, 256, 0, stream>>>(bsums, bsums, nullptr, nb1);
    add_off_kernel<<<(nKeys + 255) / 256, 256, 0, stream>>>(offs, bsums, cursor, nKeys);
    fill_kernel<<<RELS * bpr, 256, 0, stream>>>(ep, cursor, epack, E);

    long long total = (long long)N * HDIM;
    float invM = 1.f / (float)total;
    int gemmGrid = (N + 63) / 64;
    int aggGrid = (N + 3) / 4;
    int lnGrid = (int)((total / 4 + 255) / 256);

    // Layer 1: x@W1 -> Hbuf(bf16) ; agg -> d_out (+stats0)
    gemm_kernel<128, false><<<gemmGrid, 256, 0, stream>>>(x, W1, Hbuf, N, nullptr, nullptr, nullptr, invM);
    agg_kernel<<<aggGrid, 256, 0, stream>>>(Hbuf, offs, epack, b1, out, stats, N, totE);

    // Layer 2: LN1 fused into GEMM2 staging ; agg -> d_out (+stats1) ; LN2
    gemm_kernel<256, true><<<gemmGrid, 256, 0, stream>>>(out, W2, Hbuf, N, stats, ln1w, ln1b, invM);
    agg_kernel<<<aggGrid, 256, 0, stream>>>(Hbuf, offs, epack, b2, out, stats + 2, N, totE);
    ln_kernel<<<lnGrid, 256, 0, stream>>>(out, stats + 2, ln2w, ln2b, total, invM);
}

// Round 3
// 2131.457 us; speedup vs baseline: 5.8782x; 1.2517x over previous
//
#include <hip/hip_runtime.h>
#include <hip/hip_bf16.h>

// HeteroGNN R6:
// - agg: persistent grid (2048 blocks = exactly resident capacity), dst
//   assigned generation-aligned (d = wave0 + gen*8192). All resident waves
//   sweep src buckets in natural lockstep (convoy self-stabilizes: leaders
//   miss L2 and slow, laggards hit and catch up) -> per-XCD L2 holds the
//   live 4MB bucket. No grid.sync (R4 showed sync+low-MLP is 7x worse);
//   gather body identical to R5 (2 edges/instr, 12 in flight).
// - R5 evidence: MLP is saturated (1.5x MLP -> +0%); limiter is avg latency,
//   so the lever is L2 hit rate.
// - GEMM unchanged (8x8 register blocking, transposed padded A-tile).

#define RELS 4
#define HDIM 256
#define NB 16          // src buckets per dst (src>>13, src<100000 -> 0..12)
#define BSH 13

typedef float f32x4_t __attribute__((ext_vector_type(4)));
typedef unsigned short u16x8_t __attribute__((ext_vector_type(8)));

struct EdgePtrs {
    const int*   ei[RELS];
    const float* ew[RELS];
};

__device__ inline unsigned short f32_to_bf16_rne(float f) {
    unsigned int u = __float_as_uint(f);
    unsigned int r = 0x7FFFu + ((u >> 16) & 1u);
    return (unsigned short)((u + r) >> 16);
}

// ---------------- CSR build (keys = dst*NB + src_bucket) ----------------

__global__ __launch_bounds__(256) void count_kernel(EdgePtrs ep, int* __restrict__ cnts, int E) {
    int bpr = gridDim.x >> 2;
    int rel = blockIdx.x / bpr;
    int e = (blockIdx.x - rel * bpr) * 256 + threadIdx.x;
    if (e < E) {
        int src = ep.ei[rel][e];
        int dst = ep.ei[rel][E + e];
        atomicAdd(&cnts[(dst << 4) | (src >> BSH)], 1);
    }
}

template <int ITEMS>
__global__ __launch_bounds__(256) void scan_kernel(const int* __restrict__ in, int* __restrict__ out,
                                                   int* __restrict__ blockSums, int n) {
    __shared__ int wsum[4];
    int t = threadIdx.x;
    int base = blockIdx.x * 256 * ITEMS;
    int idx0 = base + t * ITEMS;
    int v[ITEMS];
    int local = 0;
#pragma unroll
    for (int j = 0; j < ITEMS; ++j) {
        v[j] = (idx0 + j < n) ? in[idx0 + j] : 0;
        local += v[j];
    }
    int lane = t & 63;
    int incl = local;
#pragma unroll
    for (int off = 1; off < 64; off <<= 1) {
        int y = __shfl_up(incl, off, 64);
        if (lane >= off) incl += y;
    }
    int waveId = t >> 6;
    if (lane == 63) wsum[waveId] = incl;
    __syncthreads();
    int waveOff = 0;
    for (int wi = 0; wi < waveId; ++wi) waveOff += wsum[wi];
    int run = waveOff + incl - local;
#pragma unroll
    for (int j = 0; j < ITEMS; ++j) {
        if (idx0 + j < n) out[idx0 + j] = run;
        run += v[j];
    }
    if (t == 255 && blockSums) blockSums[blockIdx.x] = waveOff + incl;
}

__global__ __launch_bounds__(256) void add_off_kernel(int* __restrict__ offs, const int* __restrict__ bsums,
                                                      int* __restrict__ cursor, int n) {
    int i = blockIdx.x * 256 + threadIdx.x;
    if (i < n) {
        int o = offs[i] + bsums[i >> 11];   // 2048 elems per L0 scan block
        offs[i] = o;
        cursor[i] = o;
    }
}

__global__ __launch_bounds__(256) void fill_kernel(EdgePtrs ep, int* __restrict__ cursor,
                                                   int2* __restrict__ epack, int E) {
    int bpr = gridDim.x >> 2;
    int rel = blockIdx.x / bpr;
    int e = (blockIdx.x - rel * bpr) * 256 + threadIdx.x;
    if (e < E) {
        int src = ep.ei[rel][e];
        int dst = ep.ei[rel][E + e];
        float w = ep.ew[rel][e];
        int pos = atomicAdd(&cursor[(dst << 4) | (src >> BSH)], 1);
        epack[pos] = make_int2(src, __float_as_int(w));
    }
}

// ---------------- GEMM: [M,K] x [K,256] -> bf16 [M,256] ----------------

template <int K, bool FUSE>
__global__ __launch_bounds__(256) void gemm_kernel(const float* __restrict__ A, const float* __restrict__ W,
                                                   unsigned short* __restrict__ out, int M,
                                                   const float* __restrict__ stats,
                                                   const float* __restrict__ lnw, const float* __restrict__ lnb,
                                                   float invM) {
    __shared__ float At[K * 68];
    int t = threadIdx.x;
    int rowBase = blockIdx.x * 64;
    float m = 0.f, inv = 1.f;
    if (FUSE) {
        float s = stats[0], ss = stats[1];
        m = s * invM;
        float var = ss * invM - m * m;
        inv = 1.f / (sqrtf(fmaxf(var, 0.f)) + 1e-5f);
    }
    constexpr int KQ = K / 4;
    for (int idx = t; idx < 64 * KQ; idx += 256) {
        int row = idx / KQ;
        int kq = idx - row * KQ;
        int grow = rowBase + row;
        float4 a = make_float4(0.f, 0.f, 0.f, 0.f);
        if (grow < M) a = *(const float4*)&A[(size_t)grow * K + kq * 4];
        if (FUSE) {
            float4 w4 = *(const float4*)&lnw[kq * 4];
            float4 b4 = *(const float4*)&lnb[kq * 4];
            a.x = (a.x - m) * inv * w4.x + b4.x;
            a.y = (a.y - m) * inv * w4.y + b4.y;
            a.z = (a.z - m) * inv * w4.z + b4.z;
            a.w = (a.w - m) * inv * w4.w + b4.w;
        }
        At[(kq * 4 + 0) * 68 + row] = a.x;
        At[(kq * 4 + 1) * 68 + row] = a.y;
        At[(kq * 4 + 2) * 68 + row] = a.z;
        At[(kq * 4 + 3) * 68 + row] = a.w;
    }
    __syncthreads();

    int tx = t & 31;        // col base
    int ty = t >> 5;        // row group (8 rows)
    float acc[8][8];
#pragma unroll
    for (int i = 0; i < 8; ++i)
#pragma unroll
        for (int j = 0; j < 8; ++j) acc[i][j] = 0.f;

#pragma unroll 4
    for (int k = 0; k < K; ++k) {
        float4 a0 = *(const float4*)&At[k * 68 + (ty << 3)];
        float4 a1 = *(const float4*)&At[k * 68 + (ty << 3) + 4];
        float wv[8];
#pragma unroll
        for (int j = 0; j < 8; ++j) wv[j] = W[k * HDIM + tx + (j << 5)];
#pragma unroll
        for (int j = 0; j < 8; ++j) {
            acc[0][j] += a0.x * wv[j];
            acc[1][j] += a0.y * wv[j];
            acc[2][j] += a0.z * wv[j];
            acc[3][j] += a0.w * wv[j];
            acc[4][j] += a1.x * wv[j];
            acc[5][j] += a1.y * wv[j];
            acc[6][j] += a1.z * wv[j];
            acc[7][j] += a1.w * wv[j];
        }
    }
#pragma unroll
    for (int i = 0; i < 8; ++i) {
        int row = rowBase + (ty << 3) + i;
        if (row < M) {
#pragma unroll
            for (int j = 0; j < 8; ++j)
                out[((size_t)row << 8) + tx + (j << 5)] = f32_to_bf16_rne(acc[i][j]);
        }
    }
}

// ---------------- Aggregation: persistent, generation-aligned ----------------
// Lane L: half = L>>5 selects edge parity within a pair; cl = L&31 selects the
// 16B slice (8 bf16 channels) of the 512B row. Per-lane acc covers channels
// cl*8..cl*8+7; halves combined with shfl_xor(32) per generation.

__device__ inline void acc_fma8(float* a, float w, u16x8_t u) {
#pragma unroll
    for (int k = 0; k < 8; ++k)
        a[k] += w * __uint_as_float((unsigned)u[k] << 16);
}

__global__ __launch_bounds__(256) void agg_kernel(const unsigned short* __restrict__ Hf,
                                                  const int* __restrict__ offs,
                                                  const int2* __restrict__ epack,
                                                  const float* __restrict__ bias,
                                                  float* __restrict__ outp, float* __restrict__ stats,
                                                  int nNodes, int totE) {
    const int nwaves = (int)(gridDim.x << 2);
    const int wave0 = (blockIdx.x << 2) | (threadIdx.x >> 6);
    const int lane = threadIdx.x & 63;
    const int half = lane >> 5;
    const int cl = lane & 31;
    const unsigned short* __restrict__ hbase = Hf + cl * 8;
    const float4 b0 = *(const float4*)&bias[cl * 8];
    const float4 b1 = *(const float4*)&bias[cl * 8 + 4];
    float sum = 0.f, ssq = 0.f;

    for (int gwave = wave0; gwave < nNodes; gwave += nwaves) {
        float a[8];
#pragma unroll
        for (int k = 0; k < 8; ++k) a[k] = 0.f;

        int start = __builtin_amdgcn_readfirstlane(offs[gwave << 4]);
        int endv = (gwave + 1 < nNodes) ? offs[(gwave + 1) << 4] : totE;
        int cnt = __builtin_amdgcn_readfirstlane(endv) - start;
        const long long* ep = (const long long*)epack + start;
        int i = 0;
        // 12 edges in flight: 6 per-lane edge loads + 6 paired row gathers
        for (; i + 12 <= cnt; i += 12) {
            long long q[6];
#pragma unroll
            for (int t = 0; t < 6; ++t) q[t] = ep[i + 2 * t + half];
            u16x8_t u[6];
#pragma unroll
            for (int t = 0; t < 6; ++t)
                u[t] = *(const u16x8_t*)&hbase[((size_t)(int)q[t]) << 8];
#pragma unroll
            for (int t = 0; t < 6; ++t)
                acc_fma8(a, __int_as_float((int)(q[t] >> 32)), u[t]);
        }
        for (; i + 2 <= cnt; i += 2) {
            long long q = ep[i + half];
            u16x8_t u = *(const u16x8_t*)&hbase[((size_t)(int)q) << 8];
            acc_fma8(a, __int_as_float((int)(q >> 32)), u);
        }
        if (i < cnt) {  // odd tail: both halves load same row, upper half w=0
            long long q = ep[i];
            u16x8_t u = *(const u16x8_t*)&hbase[((size_t)(int)q) << 8];
            float w = half ? 0.f : __int_as_float((int)(q >> 32));
            acc_fma8(a, w, u);
        }
        // combine even/odd halves: lane L += lane L^32
#pragma unroll
        for (int k = 0; k < 8; ++k) a[k] += __shfl_xor(a[k], 32, 64);

        a[0] += b0.x; a[1] += b0.y; a[2] += b0.z; a[3] += b0.w;
        a[4] += b1.x; a[5] += b1.y; a[6] += b1.z; a[7] += b1.w;
        if (half == 0) {
            f32x4_t v0 = {a[0], a[1], a[2], a[3]};
            f32x4_t v1 = {a[4], a[5], a[6], a[7]};
            *(f32x4_t*)&outp[((size_t)gwave << 8) + cl * 8] = v0;
            *(f32x4_t*)&outp[((size_t)gwave << 8) + cl * 8 + 4] = v1;
#pragma unroll
            for (int k = 0; k < 8; ++k) { sum += a[k]; ssq += a[k] * a[k]; }
        }
    }

#pragma unroll
    for (int off = 32; off > 0; off >>= 1) {
        sum += __shfl_down(sum, off, 64);
        ssq += __shfl_down(ssq, off, 64);
    }
    __shared__ float ls[8];
    int wid = threadIdx.x >> 6;
    if ((threadIdx.x & 63) == 0) { ls[wid] = sum; ls[4 + wid] = ssq; }
    __syncthreads();
    if (threadIdx.x == 0) {
        atomicAdd(&stats[0], ls[0] + ls[1] + ls[2] + ls[3]);
        atomicAdd(&stats[1], ls[4] + ls[5] + ls[6] + ls[7]);
    }
}

// ---------------- Graph LayerNorm (elementwise, in-place, final) ----------------

__global__ __launch_bounds__(256) void ln_kernel(float* __restrict__ data, const float* __restrict__ stats,
                                                 const float* __restrict__ lw, const float* __restrict__ lb,
                                                 long long total, float invM) {
    long long i4 = (long long)blockIdx.x * 256 + threadIdx.x;
    long long idx = i4 * 4;
    if (idx >= total) return;
    float m = stats[0] * invM;
    float var = stats[1] * invM - m * m;
    float inv = 1.f / (sqrtf(fmaxf(var, 0.f)) + 1e-5f);
    float4 v = *(float4*)&data[idx];
    int c = (int)(idx & (HDIM - 1));
    float4 w = *(const float4*)&lw[c];
    float4 b = *(const float4*)&lb[c];
    v.x = (v.x - m) * inv * w.x + b.x;
    v.y = (v.y - m) * inv * w.y + b.y;
    v.z = (v.z - m) * inv * w.z + b.z;
    v.w = (v.w - m) * inv * w.w + b.w;
    *(float4*)&data[idx] = v;
}

// ---------------- launch ----------------

extern "C" void kernel_launch(void* const* d_in, const int* in_sizes, int n_in,
                              void* d_out, int out_size, void* d_ws, size_t ws_size,
                              hipStream_t stream) {
    const float* x = (const float*)d_in[0];
    EdgePtrs ep;
    ep.ei[0] = (const int*)d_in[1]; ep.ew[0] = (const float*)d_in[2];
    ep.ei[1] = (const int*)d_in[3]; ep.ew[1] = (const float*)d_in[4];
    ep.ei[2] = (const int*)d_in[5]; ep.ew[2] = (const float*)d_in[6];
    ep.ei[3] = (const int*)d_in[7]; ep.ew[3] = (const float*)d_in[8];
    const float* W1 = (const float*)d_in[9];
    const float* b1 = (const float*)d_in[10];
    const float* W2 = (const float*)d_in[11];
    const float* b2 = (const float*)d_in[12];
    const float* ln1w = (const float*)d_in[13];
    const float* ln1b = (const float*)d_in[14];
    const float* ln2w = (const float*)d_in[15];
    const float* ln2b = (const float*)d_in[16];

    const int N = in_sizes[0] / 128;  // 100000
    const int E = in_sizes[2];        // 1600000
    const int totE = RELS * E;
    const int nKeys = N * NB;         // 1.6M
    float* out = (float*)d_out;

    // workspace layout
    char* ws = (char*)d_ws;
    unsigned short* Hbuf = (unsigned short*)ws;        // N*256 bf16 (51.2 MB)
    int2* epack = (int2*)(Hbuf + (size_t)N * HDIM);    // totE int2 (51.2 MB)
    int* cnts = (int*)(epack + totE);                  // nKeys (6.4 MB)
    int* offs = cnts + nKeys;                          // nKeys
    int* cursor = offs + nKeys;                        // nKeys
    int* bsums = cursor + nKeys;                       // 1024
    float* stats = (float*)(bsums + 1024);             // 4 floats

    hipMemsetAsync(cnts, 0, (size_t)nKeys * sizeof(int), stream);
    hipMemsetAsync(stats, 0, 4 * sizeof(float), stream);

    int bpr = (E + 255) / 256;
    count_kernel<<<RELS * bpr, 256, 0, stream>>>(ep, cnts, E);
    int nb1 = (nKeys + 2047) / 2048;   // 782 L0 blocks (ITEMS=8)
    scan_kernel<8><<<nb1, 256, 0, stream>>>(cnts, offs, bsums, nKeys);
    scan_kernel<4><<<1, 256, 0, stream>>>(bsums, bsums, nullptr, nb1);
    add_off_kernel<<<(nKeys + 255) / 256, 256, 0, stream>>>(offs, bsums, cursor, nKeys);
    fill_kernel<<<RELS * bpr, 256, 0, stream>>>(ep, cursor, epack, E);

    long long total = (long long)N * HDIM;
    float invM = 1.f / (float)total;
    int gemmGrid = (N + 63) / 64;
    // persistent agg grid: exactly resident capacity (8 blocks/CU x 256 CU);
    // generation-aligned dst mapping keeps all waves in the same src-bucket
    // window -> per-XCD L2 locality without grid.sync.
    int aggGrid = (N + 3) / 4;
    if (aggGrid > 2048) aggGrid = 2048;
    int lnGrid = (int)((total / 4 + 255) / 256);

    // Layer 1: x@W1 -> Hbuf(bf16) ; agg -> d_out (+stats0)
    gemm_kernel<128, false><<<gemmGrid, 256, 0, stream>>>(x, W1, Hbuf, N, nullptr, nullptr, nullptr, invM);
    agg_kernel<<<aggGrid, 256, 0, stream>>>(Hbuf, offs, epack, b1, out, stats, N, totE);

    // Layer 2: LN1 fused into GEMM2 staging ; agg -> d_out (+stats1) ; LN2
    gemm_kernel<256, true><<<gemmGrid, 256, 0, stream>>>(out, W2, Hbuf, N, stats, ln1w, ln1b, invM);
    agg_kernel<<<aggGrid, 256, 0, stream>>>(Hbuf, offs, epack, b2, out, stats + 2, N, totE);
    ln_kernel<<<lnGrid, 256, 0, stream>>>(out, stats + 2, ln2w, ln2b, total, invM);
}